// Round 3
// baseline (135.295 us; speedup 1.0000x reference)
//
#include <hip/hip_runtime.h>
#include <hip/hip_bf16.h>
#include <stdint.h>

#define BDIM 256

typedef __attribute__((ext_vector_type(8))) short short8;
typedef __attribute__((ext_vector_type(4))) float f32x4;

#define AS1 __attribute__((address_space(1)))
#define AS3 __attribute__((address_space(3)))
// async global->LDS DMA, 16B/lane; LDS dest must be wave-uniform base + lane*16 (m104/m108)
#define GLL16(g, s) __builtin_amdgcn_global_load_lds((AS1 const void*)(g), (AS3 void*)(s), 16, 0, 0)

__device__ __forceinline__ unsigned short f2bf(float f) {
  union { float f; unsigned u; } v; v.f = f;
  unsigned r = v.u + 0x7fffu + ((v.u >> 16) & 1u);  // round-to-nearest-even
  return (unsigned short)(r >> 16);
}
__device__ __forceinline__ float bf2f(unsigned short u) {
  union { unsigned u; float f; } v; v.u = ((unsigned)u) << 16;
  return v.f;
}

// ---- weight conversion: W1 [1024,676] -> bf16 [1024,704] zero-padded K ----
__global__ __launch_bounds__(BDIM) void cast_pad_w1(const float* __restrict__ w,
                                                    unsigned short* __restrict__ o) {
  int idx = blockIdx.x * BDIM + threadIdx.x;
  if (idx >= 1024 * 704) return;
  int n = idx / 704, k = idx - n * 704;
  float v = (k < 676) ? w[n * 676 + k] : 0.f;
  o[idx] = f2bf(v);
}

__global__ __launch_bounds__(BDIM) void cast_plain(const float* __restrict__ w,
                                                   unsigned short* __restrict__ o, int count) {
  int idx = blockIdx.x * BDIM + threadIdx.x;
  if (idx < count) o[idx] = f2bf(w[idx]);
}

// ---- conv 3x3 VALID, 28x28 -> 26x26, f32 compute, bf16 out padded 676->704 ----
__global__ __launch_bounds__(BDIM) void conv3x3(const float* __restrict__ x,
                                                const float* __restrict__ cw,
                                                unsigned short* __restrict__ h0) {
  __shared__ float xs[784];
  __shared__ float w[9];
  int m = blockIdx.x;
  const float* xr = x + (size_t)m * 784;
  if (threadIdx.x < 9) w[threadIdx.x] = cw[threadIdx.x];
  for (int i = threadIdx.x; i < 784; i += BDIM) xs[i] = xr[i];
  __syncthreads();
  unsigned short* hr = h0 + (size_t)m * 704;
  for (int p = threadIdx.x; p < 704; p += BDIM) {
    float v = 0.f;
    if (p < 676) {
      int r = p / 26, c = p - r * 26;
      const float* xp = &xs[r * 28 + c];
      v = xp[0]  * w[0] + xp[1]  * w[1] + xp[2]  * w[2]
        + xp[28] * w[3] + xp[29] * w[4] + xp[30] * w[5]
        + xp[56] * w[6] + xp[57] * w[7] + xp[58] * w[8];
    }
    hr[p] = f2bf(v);
  }
}

// ---- big-tile GEMM: C[m,n] = act(sum_k A[m,k]*Wt[n,k] + bias[n]) -> bf16 ----
// A [M,K] bf16, Wt [N,K] bf16. BMxBN tile, BK=64, 512 threads = 8 waves in a
// WGM x (8/WGM) grid; per-wave (BM/WGM)x(BN/WGN) output via 16x16x32 MFMA.
// Sync structure identical to the proven 128^2 kernel: STAGE(next buf) ->
// ds_read+MFMA(cur) -> one drain barrier per K-tile.
template <int BM, int BN, int WGM, bool RELU>
__global__ __launch_bounds__(512, 2) void gemm_bt2(const unsigned short* __restrict__ A,
                                                   const unsigned short* __restrict__ Wt,
                                                   const float* __restrict__ bias,
                                                   unsigned short* __restrict__ Cb,
                                                   int M, int N, int K) {
  constexpr int WGN = 8 / WGM;
  constexpr int FM = BM / WGM / 16;   // M-fragments per wave
  constexpr int FN = BN / WGN / 16;   // N-fragments per wave
  constexpr int RA = BM / 64;         // 64-row staging rounds for A
  constexpr int RB = BN / 64;
  __shared__ unsigned short As[2][BM * 64];
  __shared__ unsigned short Bs[2][BN * 64];
  const int tid = threadIdx.x;
  const int lane = tid & 63;
  const int wid = tid >> 6;
  const int nbm = M / BM;
  const int brow = (blockIdx.x % nbm) * BM;
  const int bcol = (blockIdx.x / nbm) * BN;

  // staging: round r covers rows [r*64, r*64+64); thread t -> row r*64+t/8,
  // cols (t%8)*8..+8. LDS dest = base + t*16B: linear, wave-uniform+lane*16. ✓
  const int srow = tid >> 3;
  const int scol = (tid & 7) << 3;
  const unsigned short* gA = A + (size_t)(brow + srow) * K + scol;
  const unsigned short* gB = Wt + (size_t)(bcol + srow) * K + scol;
  const int sdst = tid * 8;  // elements

#define STAGE(buf, kt)                                                        \
  do {                                                                        \
    _Pragma("unroll")                                                         \
    for (int r = 0; r < RA; ++r)                                              \
      GLL16(gA + (size_t)r * 64 * K + (kt) * 64, &As[buf][r * 4096 + sdst]);  \
    _Pragma("unroll")                                                         \
    for (int r = 0; r < RB; ++r)                                              \
      GLL16(gB + (size_t)r * 64 * K + (kt) * 64, &Bs[buf][r * 4096 + sdst]);  \
  } while (0)

  f32x4 acc[FM][FN] = {};

  const int fr = lane & 15;            // row within 16x16 fragment
  const int g8 = (lane >> 4) << 3;     // k-subgroup offset 0/8/16/24
  const int abase = (wid / WGN) * (FM * 16);
  const int bbase = (wid % WGN) * (FN * 16);

  const int nk = K >> 6;
  STAGE(0, 0);
  __syncthreads();
  int cur = 0;
  for (int kt = 0; kt < nk; ++kt) {
    if (kt + 1 < nk) STAGE(cur ^ 1, kt + 1);   // prefetch overlaps MFMA
#pragma unroll
    for (int s = 0; s < 2; ++s) {              // two 32-wide K slices of BK=64
      short8 af[FM], bf[FN];
#pragma unroll
      for (int m = 0; m < FM; ++m)
        af[m] = *(const short8*)&As[cur][(abase + m * 16 + fr) * 64 + s * 32 + g8];
#pragma unroll
      for (int n = 0; n < FN; ++n)
        bf[n] = *(const short8*)&Bs[cur][(bbase + n * 16 + fr) * 64 + s * 32 + g8];
#pragma unroll
      for (int m = 0; m < FM; ++m)
#pragma unroll
        for (int n = 0; n < FN; ++n)
          acc[m][n] = __builtin_amdgcn_mfma_f32_16x16x32_bf16(af[m], bf[n], acc[m][n], 0, 0, 0);
    }
    __syncthreads();                           // readers done + DMA drained
    cur ^= 1;
  }
#undef STAGE

  // epilogue: frag (m,n) elem j -> C[row0 + m*16 + j][col0 + n*16] (m89/m91 layout)
  const int crow0 = brow + abase + ((lane >> 4) << 2);
  const int ccol0 = bcol + bbase + fr;
#pragma unroll
  for (int n = 0; n < FN; ++n) {
    const int cc = ccol0 + n * 16;
    const float bv = bias[cc];
#pragma unroll
    for (int m = 0; m < FM; ++m) {
      const int rr = crow0 + m * 16;
#pragma unroll
      for (int j = 0; j < 4; ++j) {
        float v = acc[m][n][j] + bv;
        if (RELU) v = v > 0.f ? v : 0.f;
        Cb[(size_t)(rr + j) * N + cc] = f2bf(v);
      }
    }
  }
}

// ---- final layer: out[m,n] = sum_k h3[m,k]*W4[n,k] + b4[n], N=10, K=256, f32 out ----
__global__ __launch_bounds__(BDIM) void fc10(const unsigned short* __restrict__ h3,
                                             const float* __restrict__ W4,
                                             const float* __restrict__ b4,
                                             float* __restrict__ out) {
  int lane = threadIdx.x & 63;
  int wid = threadIdx.x >> 6;
  int m = blockIdx.x * 4 + wid;
  const unsigned short* hr = h3 + (size_t)m * 256 + lane * 4;
  uint64_t hv = *(const uint64_t*)hr;
  float e0 = bf2f((unsigned short)hv), e1 = bf2f((unsigned short)(hv >> 16));
  float e2 = bf2f((unsigned short)(hv >> 32)), e3 = bf2f((unsigned short)(hv >> 48));
#pragma unroll
  for (int n = 0; n < 10; ++n) {
    const float4 wv = *(const float4*)(W4 + n * 256 + lane * 4);
    float s = e0 * wv.x + e1 * wv.y + e2 * wv.z + e3 * wv.w;
#pragma unroll
    for (int off = 32; off > 0; off >>= 1) s += __shfl_xor(s, off);
    if (lane == n) out[(size_t)m * 10 + n] = s + b4[n];
  }
}

extern "C" void kernel_launch(void* const* d_in, const int* in_sizes, int n_in,
                              void* d_out, int out_size, void* d_ws, size_t ws_size,
                              hipStream_t stream) {
  const float* x  = (const float*)d_in[0];
  const float* cw = (const float*)d_in[1];
  const float* W1 = (const float*)d_in[2];
  const float* b1 = (const float*)d_in[3];
  const float* W2 = (const float*)d_in[4];
  const float* b2 = (const float*)d_in[5];
  const float* W3 = (const float*)d_in[6];
  const float* b3 = (const float*)d_in[7];
  const float* W4 = (const float*)d_in[8];
  const float* b4 = (const float*)d_in[9];
  float* out = (float*)d_out;

  char* ws = (char*)d_ws;
  // h0 [16384,704] bf16 (23,068,672 B) — region reused for h2 [16384,512]
  // h1 [16384,1024] bf16 (33,554,432 B) — region reused for h3 [16384,256]
  unsigned short* h0  = (unsigned short*)(ws);
  unsigned short* h1  = (unsigned short*)(ws + 23068672);
  unsigned short* W1b = (unsigned short*)(ws + 23068672 + 33554432);
  unsigned short* W2b = W1b + 1024 * 704;
  unsigned short* W3b = W2b + 512 * 1024;
  unsigned short* h2  = h0;
  unsigned short* h3  = h1;

  cast_pad_w1<<<2816, BDIM, 0, stream>>>(W1, W1b);
  cast_plain<<<2048, BDIM, 0, stream>>>(W2, W2b, 512 * 1024);
  cast_plain<<<512, BDIM, 0, stream>>>(W3, W3b, 256 * 512);
  conv3x3<<<16384, BDIM, 0, stream>>>(x, cw, h0);

  // GEMM1: M=16384 N=1024 K=704 (11 K-tiles of 64). grid 64*4=256 = 1 block/CU.
  gemm_bt2<256, 256, 2, true><<<(16384 / 256) * (1024 / 256), 512, 0, stream>>>(
      h0, W1b, b1, h1, 16384, 1024, 704);
  // GEMM2: M=16384 N=512 K=1024 (16 K-tiles). BN=128 keeps grid at 256.
  gemm_bt2<256, 128, 4, true><<<(16384 / 256) * (512 / 128), 512, 0, stream>>>(
      h1, W2b, b2, h2, 16384, 512, 1024);
  // GEMM3: M=16384 N=256 K=512 (8 K-tiles). 128x128 keeps grid at 256.
  gemm_bt2<128, 128, 4, true><<<(16384 / 128) * (256 / 128), 512, 0, stream>>>(
      h2, W3b, b3, h3, 16384, 256, 512);
  fc10<<<16384 / 4, BDIM, 0, stream>>>(h3, W4, b4, out);
}

// Round 4
// 110.082 us; speedup vs baseline: 1.2290x; 1.2290x over previous
//
#include <hip/hip_runtime.h>
#include <hip/hip_bf16.h>
#include <stdint.h>

#define BDIM 256

typedef __attribute__((ext_vector_type(8))) short short8;
typedef __attribute__((ext_vector_type(4))) float f32x4;

#define AS1 __attribute__((address_space(1)))
#define AS3 __attribute__((address_space(3)))
// async global->LDS DMA, 16B/lane; LDS dest must be wave-uniform base + lane*16 (m104/m108)
#define GLL16(g, s) __builtin_amdgcn_global_load_lds((AS1 const void*)(g), (AS3 void*)(s), 16, 0, 0)

__device__ __forceinline__ unsigned short f2bf(float f) {
  union { float f; unsigned u; } v; v.f = f;
  unsigned r = v.u + 0x7fffu + ((v.u >> 16) & 1u);  // round-to-nearest-even
  return (unsigned short)(r >> 16);
}
__device__ __forceinline__ float bf2f(unsigned short u) {
  union { unsigned u; float f; } v; v.u = ((unsigned)u) << 16;
  return v.f;
}

// ---- weight conversion: W1 [1024,676] -> bf16 [1024,704] zero-padded K ----
__global__ __launch_bounds__(BDIM) void cast_pad_w1(const float* __restrict__ w,
                                                    unsigned short* __restrict__ o) {
  int idx = blockIdx.x * BDIM + threadIdx.x;
  if (idx >= 1024 * 704) return;
  int n = idx / 704, k = idx - n * 704;
  float v = (k < 676) ? w[n * 676 + k] : 0.f;
  o[idx] = f2bf(v);
}

__global__ __launch_bounds__(BDIM) void cast_plain(const float* __restrict__ w,
                                                   unsigned short* __restrict__ o, int count) {
  int idx = blockIdx.x * BDIM + threadIdx.x;
  if (idx < count) o[idx] = f2bf(w[idx]);
}

// ---- conv 3x3 VALID, 28x28 -> 26x26, f32 compute, bf16 out padded 676->704 ----
__global__ __launch_bounds__(BDIM) void conv3x3(const float* __restrict__ x,
                                                const float* __restrict__ cw,
                                                unsigned short* __restrict__ h0) {
  __shared__ float xs[784];
  __shared__ float w[9];
  int m = blockIdx.x;
  const float* xr = x + (size_t)m * 784;
  if (threadIdx.x < 9) w[threadIdx.x] = cw[threadIdx.x];
  for (int i = threadIdx.x; i < 784; i += BDIM) xs[i] = xr[i];
  __syncthreads();
  unsigned short* hr = h0 + (size_t)m * 704;
  for (int p = threadIdx.x; p < 704; p += BDIM) {
    float v = 0.f;
    if (p < 676) {
      int r = p / 26, c = p - r * 26;
      const float* xp = &xs[r * 28 + c];
      v = xp[0]  * w[0] + xp[1]  * w[1] + xp[2]  * w[2]
        + xp[28] * w[3] + xp[29] * w[4] + xp[30] * w[5]
        + xp[56] * w[6] + xp[57] * w[7] + xp[58] * w[8];
    }
    hr[p] = f2bf(v);
  }
}

// ---- big-tile GEMM: C[m,n] = act(sum_k A[m,k]*Wt[n,k] + bias[n]) -> bf16 ----
// A [M,K] bf16, Wt [N,K] bf16. BMxBN tile, BK=64, 512 threads = 8 waves.
// 2-phase sync structure (STAGE next -> ds_read+MFMA cur -> barrier), with:
//  * K-tile XOR swizzle (slot ^= row&7), rule-21 form: linear gload_lds dest +
//    pre-swizzled GLOBAL source + same XOR on ds_read -> conflict-free frags.
//  * LDS-transpose epilogue: frags -> swizzled LDS scratch -> full-line 16B
//    coalesced stores (kills the 2.4x HBM write RMW amplification).
template <int BM, int BN, int WGM, bool RELU>
__global__ __launch_bounds__(512, 2) void gemm_bt2(const unsigned short* __restrict__ A,
                                                   const unsigned short* __restrict__ Wt,
                                                   const float* __restrict__ bias,
                                                   unsigned short* __restrict__ Cb,
                                                   int M, int N, int K) {
  constexpr int WGN = 8 / WGM;
  constexpr int FM = BM / WGM / 16;   // M-fragments per wave
  constexpr int FN = BN / WGN / 16;   // N-fragments per wave
  constexpr int RA = BM / 64;         // 64-row staging rounds for A
  constexpr int RB = BN / 64;
  __shared__ unsigned short lds[(size_t)(BM + BN) * 128];
  unsigned short* const Asb = lds;                 // [2][BM*64]
  unsigned short* const Bsb = lds + 2 * BM * 64;   // [2][BN*64]

  const int tid = threadIdx.x;
  const int lane = tid & 63;
  const int wid = tid >> 6;
  const int nbm = M / BM;
  const int brow = (blockIdx.x % nbm) * BM;
  const int bcol = (blockIdx.x / nbm) * BN;

  // staging: round r covers tile rows [r*64, r*64+64). Thread t -> row r*64+t/8.
  // LDS dest linear (t*16B). Source 16B-slot is PRE-SWIZZLED: slot ^ (row&7),
  // so that LDS[row][q] = tile[row][q ^ (row&7)] (involution; reads undo it).
  const int srow = tid >> 3;
  const int sslot = (tid & 7) ^ (srow & 7);
  const unsigned short* gA = A + (size_t)(brow + srow) * K + sslot * 8;
  const unsigned short* gB = Wt + (size_t)(bcol + srow) * K + sslot * 8;
  const int sdst = tid * 8;  // elements

#define STAGE(buf, kt)                                                            \
  do {                                                                            \
    _Pragma("unroll")                                                             \
    for (int r = 0; r < RA; ++r)                                                  \
      GLL16(gA + (size_t)r * 64 * K + (size_t)(kt) * 64,                          \
            Asb + (buf) * BM * 64 + r * 4096 + sdst);                             \
    _Pragma("unroll")                                                             \
    for (int r = 0; r < RB; ++r)                                                  \
      GLL16(gB + (size_t)r * 64 * K + (size_t)(kt) * 64,                          \
            Bsb + (buf) * BN * 64 + r * 4096 + sdst);                             \
  } while (0)

  f32x4 acc[FM][FN] = {};

  const int fr = lane & 15;            // row within 16x16 fragment
  const int h = lane >> 4;             // k-subgroup 0..3 (8 elems each)
  const int fx = fr & 7;               // read-side swizzle XOR (= row&7)
  const int abase = (wid / WGN) * (FM * 16);
  const int bbase = (wid % WGN) * (FN * 16);

  const int nk = K >> 6;
  STAGE(0, 0);
  __syncthreads();
  int cur = 0;
  for (int kt = 0; kt < nk; ++kt) {
    if (kt + 1 < nk) STAGE(cur ^ 1, kt + 1);   // prefetch overlaps MFMA
#pragma unroll
    for (int s = 0; s < 2; ++s) {              // two 32-wide K slices of BK=64
      const int slot = (((s << 2) + h) ^ fx) << 3;  // swizzled element offset
      short8 af[FM], bf[FN];
#pragma unroll
      for (int m = 0; m < FM; ++m)
        af[m] = *(const short8*)&Asb[cur * BM * 64 + (abase + m * 16 + fr) * 64 + slot];
#pragma unroll
      for (int n = 0; n < FN; ++n)
        bf[n] = *(const short8*)&Bsb[cur * BN * 64 + (bbase + n * 16 + fr) * 64 + slot];
#pragma unroll
      for (int m = 0; m < FM; ++m)
#pragma unroll
        for (int n = 0; n < FN; ++n)
          acc[m][n] = __builtin_amdgcn_mfma_f32_16x16x32_bf16(af[m], bf[n], acc[m][n], 0, 0, 0);
    }
    __syncthreads();                           // readers done + DMA drained
    cur ^= 1;
  }
#undef STAGE

  // ---- epilogue: frags -> LDS scratch (swizzled) -> coalesced 16B stores ----
  // All staging buffers are dead after the loop-end barrier; reuse lds as a
  // [BM][BN] bf16 scratch with element XOR ((row&12)<<2): the 4 row-groups of
  // a wave-store land on disjoint 16-element blocks -> disjoint bank octets.
  unsigned short* const scr = lds;  // BM*BN <= (BM+BN)*128 for all configs here
  const int lrow0 = abase + (h << 2);  // local row of j=0
  const int lcol0 = bbase + fr;
#pragma unroll
  for (int n = 0; n < FN; ++n) {
    const int col = lcol0 + n * 16;
    const float bv = bias[bcol + col];
#pragma unroll
    for (int m = 0; m < FM; ++m) {
#pragma unroll
      for (int j = 0; j < 4; ++j) {
        const int row = lrow0 + m * 16 + j;
        float v = acc[m][n][j] + bv;
        if (RELU) v = v > 0.f ? v : 0.f;
        scr[(row * BN + col) ^ ((row & 12) << 2)] = f2bf(v);
      }
    }
  }
  __syncthreads();
  constexpr int CPR = BN / 8;        // 16B chunks per row
  constexpr int TOT = BM * CPR;
#pragma unroll 2
  for (int i = tid; i < TOT; i += 512) {
    const int row = i / CPR, c = i % CPR;
    const int cs = c ^ ((row & 12) >> 1);     // same XOR at chunk granularity
    short8 vv = *(const short8*)&scr[row * BN + cs * 8];
    *(short8*)(Cb + (size_t)(brow + row) * N + bcol + c * 8) = vv;
  }
}

// ---- final layer: out[m,n] = sum_k h3[m,k]*W4[n,k] + b4[n], N=10, K=256, f32 out ----
__global__ __launch_bounds__(BDIM) void fc10(const unsigned short* __restrict__ h3,
                                             const float* __restrict__ W4,
                                             const float* __restrict__ b4,
                                             float* __restrict__ out) {
  int lane = threadIdx.x & 63;
  int wid = threadIdx.x >> 6;
  int m = blockIdx.x * 4 + wid;
  const unsigned short* hr = h3 + (size_t)m * 256 + lane * 4;
  uint64_t hv = *(const uint64_t*)hr;
  float e0 = bf2f((unsigned short)hv), e1 = bf2f((unsigned short)(hv >> 16));
  float e2 = bf2f((unsigned short)(hv >> 32)), e3 = bf2f((unsigned short)(hv >> 48));
#pragma unroll
  for (int n = 0; n < 10; ++n) {
    const float4 wv = *(const float4*)(W4 + n * 256 + lane * 4);
    float s = e0 * wv.x + e1 * wv.y + e2 * wv.z + e3 * wv.w;
#pragma unroll
    for (int off = 32; off > 0; off >>= 1) s += __shfl_xor(s, off);
    if (lane == n) out[(size_t)m * 10 + n] = s + b4[n];
  }
}

extern "C" void kernel_launch(void* const* d_in, const int* in_sizes, int n_in,
                              void* d_out, int out_size, void* d_ws, size_t ws_size,
                              hipStream_t stream) {
  const float* x  = (const float*)d_in[0];
  const float* cw = (const float*)d_in[1];
  const float* W1 = (const float*)d_in[2];
  const float* b1 = (const float*)d_in[3];
  const float* W2 = (const float*)d_in[4];
  const float* b2 = (const float*)d_in[5];
  const float* W3 = (const float*)d_in[6];
  const float* b3 = (const float*)d_in[7];
  const float* W4 = (const float*)d_in[8];
  const float* b4 = (const float*)d_in[9];
  float* out = (float*)d_out;

  char* ws = (char*)d_ws;
  // h0 [16384,704] bf16 (23,068,672 B) — region reused for h2 [16384,512]
  // h1 [16384,1024] bf16 (33,554,432 B) — region reused for h3 [16384,256]
  unsigned short* h0  = (unsigned short*)(ws);
  unsigned short* h1  = (unsigned short*)(ws + 23068672);
  unsigned short* W1b = (unsigned short*)(ws + 23068672 + 33554432);
  unsigned short* W2b = W1b + 1024 * 704;
  unsigned short* W3b = W2b + 512 * 1024;
  unsigned short* h2  = h0;
  unsigned short* h3  = h1;

  cast_pad_w1<<<2816, BDIM, 0, stream>>>(W1, W1b);
  cast_plain<<<2048, BDIM, 0, stream>>>(W2, W2b, 512 * 1024);
  cast_plain<<<512, BDIM, 0, stream>>>(W3, W3b, 256 * 512);
  conv3x3<<<16384, BDIM, 0, stream>>>(x, cw, h0);

  // GEMM1: M=16384 N=1024 K=704 (11 K-tiles of 64). grid 64*4=256 = 1 block/CU.
  gemm_bt2<256, 256, 2, true><<<(16384 / 256) * (1024 / 256), 512, 0, stream>>>(
      h0, W1b, b1, h1, 16384, 1024, 704);
  // GEMM2: M=16384 N=512 K=1024 (16 K-tiles). BN=128 keeps grid at 256.
  gemm_bt2<256, 128, 4, true><<<(16384 / 256) * (512 / 128), 512, 0, stream>>>(
      h1, W2b, b2, h2, 16384, 512, 1024);
  // GEMM3: M=16384 N=256 K=512 (8 K-tiles). 128x128 -> 2 blocks/CU.
  gemm_bt2<128, 128, 4, true><<<(16384 / 128) * (256 / 128), 512, 0, stream>>>(
      h2, W3b, b3, h3, 16384, 256, 512);
  fc10<<<16384 / 4, BDIM, 0, stream>>>(h3, W4, b4, out);
}